// Round 10
// baseline (251.522 us; speedup 1.0000x reference)
//
#include <hip/hip_runtime.h>
#include <hip/hip_bf16.h>

#define NN 30000
#define EE 480000
#define C  128
#define TEDGE 32
#define NTILES (EE / TEDGE)   // 15000

typedef __attribute__((ext_vector_type(8))) short          short8v;
typedef __attribute__((ext_vector_type(8))) unsigned short ushort8v;
typedef __attribute__((ext_vector_type(8))) short          frag16;   // 8 bf16
typedef __attribute__((ext_vector_type(4))) float          f32x4;

#define MFMA16(a, b, c) __builtin_amdgcn_mfma_f32_16x16x32_bf16(a, b, c, 0, 0, 0)

static __device__ __forceinline__ unsigned short f2bf_rn(float f) {
    unsigned int u = __float_as_uint(f);
    unsigned int r = (u + 0x7fffu + ((u >> 16) & 1u)) >> 16;
    return (unsigned short)r;
}
static __device__ __forceinline__ float bf2f(unsigned short s) {
    return __uint_as_float(((unsigned int)s) << 16);
}
// HW packed convert: 2 f32 -> 1 dword (2x bf16). gfx950-only, no builtin (T12).
static __device__ __forceinline__ unsigned int f2bf_pk(float lo, float hi) {
    unsigned int r;
    asm("v_cvt_pk_bf16_f32 %0, %1, %2" : "=v"(r) : "v"(lo), "v"(hi));
    return r;
}
union PK8 { short8v s; unsigned int u[4]; };
union PK4 { ushort4 q; unsigned int u[2]; };

// ---------------- P0: weight precomputes (all outputs TRANSPOSED bf16) ------
__global__ __launch_bounds__(256) void prep_kernel(
    const float* __restrict__ pm_w2, const float* __restrict__ at_w1,
    const float* __restrict__ Wq, const float* __restrict__ Wk,
    const float* __restrict__ Wv, const float* __restrict__ root_w,
    const float* __restrict__ pm_b2, const float* __restrict__ at_b1,
    unsigned short* __restrict__ WcT, unsigned short* __restrict__ WqaT,
    unsigned short* __restrict__ WkaT, unsigned short* __restrict__ WvT,
    unsigned short* __restrict__ WrT, unsigned short* __restrict__ Wp2T,
    float* __restrict__ bias_c)
{
    const int which = blockIdx.y;
    const int t = threadIdx.x;
    const int i = blockIdx.x * 2 + (t >> 7), j = t & 127;

    if (which == 3) {
        if (blockIdx.x == 0 && t < C) {
            float s = at_b1[t];
            for (int k = 0; k < C; ++k) s = fmaf(pm_b2[k], at_w1[k * C + t], s);
            bias_c[t] = s;
        }
        return;
    }
    if (which >= 4) {
        const float* A = (which == 4) ? Wv : (which == 5) ? root_w : pm_w2;
        unsigned short* OT = (which == 4) ? WvT : (which == 5) ? WrT : Wp2T;
        OT[j * C + i] = f2bf_rn(A[i * C + j]);
        return;
    }
    const float* A = (which == 0) ? pm_w2 : (which == 1) ? Wq : Wk;
    unsigned short* OT = (which == 0) ? WcT : (which == 1) ? WqaT : WkaT;

    __shared__ float sA[2][C];
    sA[t >> 7][j] = A[i * C + j];
    __syncthreads();
    float s = 0.f;
    for (int k = 0; k < C; ++k) s = fmaf(sA[t >> 7][k], at_w1[k * C + j], s);
    OT[j * C + i] = f2bf_rn(s);
}

// ---------------- K1: node GEMMs via MFMA (stages f32 x -> bf16 LDS) --------
__global__ __launch_bounds__(256, 4) void node_gemm(
    const float* __restrict__ x,
    const unsigned short* __restrict__ WvT, const unsigned short* __restrict__ WqaT,
    const unsigned short* __restrict__ WkaT, const unsigned short* __restrict__ WrT,
    const float* __restrict__ root_b,
    unsigned short* __restrict__ vbf, unsigned short* __restrict__ qabf,
    unsigned short* __restrict__ kabf, float* __restrict__ out)
{
    __shared__ short s_x[64 * C];   // bf16, swizzled
    const int nb = blockIdx.x * 64;
    const int t = threadIdx.x;
    const int lane = t & 63, wv = t >> 6;
    const int ln15 = lane & 15, lg = lane >> 4;
    const int jw = wv * 32;

    {   // stage x tile (f32 -> bf16, packed converts)
        const int rq = t >> 2, q4 = t & 3;
        int row = nb + rq;
        #pragma unroll
        for (int i2 = 0; i2 < 4; ++i2) {
            int j0 = q4 * 32 + i2 * 8;
            PK8 o;
            if (row < NN) {
                float4 a = *(const float4*)(x + (size_t)row * C + j0);
                float4 b = *(const float4*)(x + (size_t)row * C + j0 + 4);
                o.u[0] = f2bf_pk(a.x, a.y);
                o.u[1] = f2bf_pk(a.z, a.w);
                o.u[2] = f2bf_pk(b.x, b.y);
                o.u[3] = f2bf_pk(b.z, b.w);
            } else {
                o.u[0] = o.u[1] = o.u[2] = o.u[3] = 0u;
            }
            int off = (rq * 256 + j0 * 2) ^ ((rq & 7) << 4);
            *(short8v*)((char*)s_x + off) = o.s;
        }
    }
    __syncthreads();

    for (int m = 0; m < 4; ++m) {
        const unsigned short* WT;
        switch (m) {
            case 0: WT = WvT;  break; case 1: WT = WqaT; break;
            case 2: WT = WkaT; break; default: WT = WrT;
        }
        frag16 aW[2][4];
        #pragma unroll
        for (int nt = 0; nt < 2; ++nt)
            #pragma unroll
            for (int ks = 0; ks < 4; ++ks)
                aW[nt][ks] = *(const frag16*)(WT + (size_t)(jw + nt * 16 + ln15) * C
                                                 + ks * 32 + lg * 8);
        f32x4 acc[4][2];
        const f32x4 zz = {0.f, 0.f, 0.f, 0.f};
        #pragma unroll
        for (int mt = 0; mt < 4; ++mt) { acc[mt][0] = zz; acc[mt][1] = zz; }

        #pragma unroll
        for (int mt = 0; mt < 4; ++mt) {
            int row = mt * 16 + ln15;
            #pragma unroll
            for (int ks = 0; ks < 4; ++ks) {
                int off = (row * 256 + (ks * 32 + lg * 8) * 2) ^ ((row & 7) << 4);
                frag16 b = *(const frag16*)((const char*)s_x + off);
                acc[mt][0] = MFMA16(aW[0][ks], b, acc[mt][0]);
                acc[mt][1] = MFMA16(aW[1][ks], b, acc[mt][1]);
            }
        }

        if (m == 3) {
            #pragma unroll
            for (int nt = 0; nt < 2; ++nt) {
                int col0 = jw + nt * 16 + lg * 4;
                float4 rb = *(const float4*)(root_b + col0);
                #pragma unroll
                for (int mt = 0; mt < 4; ++mt) {
                    int node = nb + mt * 16 + ln15;
                    if (node < NN) {
                        float4 o;
                        o.x = acc[mt][nt][0] + rb.x; o.y = acc[mt][nt][1] + rb.y;
                        o.z = acc[mt][nt][2] + rb.z; o.w = acc[mt][nt][3] + rb.w;
                        *(float4*)(out + (size_t)node * C + col0) = o;
                    }
                }
            }
        } else {
            unsigned short* OB = (m == 0) ? vbf : (m == 1) ? qabf : kabf;
            #pragma unroll
            for (int nt = 0; nt < 2; ++nt) {
                int col0 = jw + nt * 16 + lg * 4;
                #pragma unroll
                for (int mt = 0; mt < 4; ++mt) {
                    int node = nb + mt * 16 + ln15;
                    if (node < NN) {
                        PK4 cv;
                        cv.u[0] = f2bf_pk(acc[mt][nt][0], acc[mt][nt][1]);
                        cv.u[1] = f2bf_pk(acc[mt][nt][2], acc[mt][nt][3]);
                        *(ushort4*)(OB + (size_t)node * C + col0) = cv.q;
                    }
                }
            }
        }
    }
}

// ---------------- K3: CSR build by destination ----------------
__global__ __launch_bounds__(256) void hist_kernel(const int* __restrict__ eidx,
                                                   int* __restrict__ counts)
{
    int e = blockIdx.x * 256 + threadIdx.x;
    if (e < EE) atomicAdd(&counts[eidx[EE + e]], 1);
}

__global__ __launch_bounds__(1024) void scan_kernel(const int* __restrict__ counts,
                                                    int* __restrict__ offsets, int n)
{
    __shared__ int wsum[16];
    __shared__ int wpre[16];
    __shared__ int tot_s;
    int t = threadIdx.x;
    int lane = t & 63, w = t >> 6;
    int carry = 0;
    for (int base = 0; base < n; base += 1024) {
        int i = base + t;
        int v = (i < n) ? counts[i] : 0;
        int incl = v;
        #pragma unroll
        for (int d = 1; d < 64; d <<= 1) {
            int u = __shfl_up(incl, d, 64);
            if (lane >= d) incl += u;
        }
        if (lane == 63) wsum[w] = incl;
        __syncthreads();
        if (t == 0) {
            int run = 0;
            #pragma unroll
            for (int ww = 0; ww < 16; ++ww) { wpre[ww] = run; run += wsum[ww]; }
            tot_s = run;
        }
        __syncthreads();
        if (i < n) offsets[i] = carry + wpre[w] + incl - v;
        carry += tot_s;
        __syncthreads();
    }
    if (t == 0) offsets[n] = carry;
}

__global__ __launch_bounds__(256) void fill_kernel(const int* __restrict__ eidx,
                                                   const float* __restrict__ pos,
                                                   const int* __restrict__ offsets,
                                                   int* __restrict__ cursor,
                                                   int* __restrict__ rows_sorted,
                                                   int* __restrict__ cols_sorted,
                                                   float* __restrict__ dpos4)
{
    int e = blockIdx.x * 256 + threadIdx.x;
    if (e < EE) {
        int r = eidx[e];
        int c = eidx[EE + e];
        int p = atomicAdd(&cursor[c], 1);
        int slot = offsets[c] + p;
        rows_sorted[slot] = r;
        cols_sorted[slot] = c;
        float4 d;
        d.x = pos[r * 3 + 0] - pos[c * 3 + 0];
        d.y = pos[r * 3 + 1] - pos[c * 3 + 1];
        d.z = pos[r * 3 + 2] - pos[c * 3 + 2];
        d.w = 0.f;
        *(float4*)(dpos4 + (size_t)slot * 4) = d;
    }
}

// ---------------- K2: per-edge logits via MFMA, 32-edge tiles ---------------
// Half-size tiles double resident blocks/CU (LDS 17.7 KB -> 8 blocks/CU):
// the kernel is latency-bound on the qa/ka gathers, concurrency is the lever.
__global__ __launch_bounds__(256, 4) void edge_kernel(
    const int* __restrict__ rows_sorted, const int* __restrict__ cols_sorted,
    const float* __restrict__ dpos4,
    const unsigned short* __restrict__ qabf, const unsigned short* __restrict__ kabf,
    const float* __restrict__ pm_w1, const float* __restrict__ pm_b1,
    const unsigned short* __restrict__ WcT, const float* __restrict__ bias_c,
    const float* __restrict__ at_w2, const float* __restrict__ at_b2,
    float* __restrict__ logits)
{
    __shared__ short s_t1[TEDGE * C];    // bf16, swizzled (8 KB)
    __shared__ short s_qka[TEDGE * C];   // bf16, swizzled (8 KB)
    __shared__ float s_dp[TEDGE][4];
    __shared__ int   s_row[TEDGE], s_col[TEDGE];
    __shared__ float s_logit[TEDGE][4];

    const int t = threadIdx.x;
    const int lane = t & 63, wv = t >> 6;
    const int ln15 = lane & 15, lg = lane >> 4;
    const int jw = wv * 32;
    const int rt = t >> 4, ct8 = (t & 15) * 8;
    const int rq = t >> 3, q8 = t & 7;
    const int s0 = blockIdx.x * TEDGE;

    // metadata stage
    if (t < TEDGE) {
        s_row[t] = rows_sorted[s0 + t];
        s_col[t] = cols_sorted[s0 + t];
        *(float4*)(&s_dp[t][0]) = *(const float4*)(dpos4 + (size_t)(s0 + t) * 4);
    }

    // pm_w1/pm_b1 slice in registers
    float w1xr[8], w1yr[8], w1zr[8], w1br[8];
    #pragma unroll
    for (int e = 0; e < 8; ++e) {
        int j = ct8 + e;
        w1xr[e] = pm_w1[j];
        w1yr[e] = pm_w1[C + j];
        w1zr[e] = pm_w1[2 * C + j];
        w1br[e] = pm_b1[j];
    }

    // per-lane epilogue constants: cols jw + nt*16 + lg*4 + r
    float bcv[8], w2v[8];
    #pragma unroll
    for (int nt = 0; nt < 2; ++nt) {
        int col0 = jw + nt * 16 + lg * 4;
        float4 b4 = *(const float4*)(bias_c + col0);
        float4 w4 = *(const float4*)(at_w2 + col0);
        bcv[nt * 4 + 0] = b4.x; bcv[nt * 4 + 1] = b4.y;
        bcv[nt * 4 + 2] = b4.z; bcv[nt * 4 + 3] = b4.w;
        w2v[nt * 4 + 0] = w4.x; w2v[nt * 4 + 1] = w4.y;
        w2v[nt * 4 + 2] = w4.z; w2v[nt * 4 + 3] = w4.w;
    }
    const float atb2 = at_b2[0];

    frag16 aW[2][4];
    #pragma unroll
    for (int nt = 0; nt < 2; ++nt)
        #pragma unroll
        for (int ks = 0; ks < 4; ++ks)
            aW[nt][ks] = *(const frag16*)(WcT + (size_t)(jw + nt * 16 + ln15) * C
                                             + ks * 32 + lg * 8);
    __syncthreads();   // metadata ready

    // stage qka = qa[col] - ka[row]: 8 threads/row, 16 cols each (2 chunks)
    {
        const unsigned short* qrow = qabf + (size_t)s_col[rq] * C;
        const unsigned short* krow = kabf + (size_t)s_row[rq] * C;
        #pragma unroll
        for (int i2 = 0; i2 < 2; ++i2) {
            int j0 = q8 * 16 + i2 * 8;
            ushort8v qa8 = *(const ushort8v*)(qrow + j0);
            ushort8v ka8 = *(const ushort8v*)(krow + j0);
            PK8 o;
            #pragma unroll
            for (int p = 0; p < 4; ++p) {
                float a0 = bf2f(qa8[2 * p])     - bf2f(ka8[2 * p]);
                float a1 = bf2f(qa8[2 * p + 1]) - bf2f(ka8[2 * p + 1]);
                o.u[p] = f2bf_pk(a0, a1);
            }
            int off = (rq * 256 + j0 * 2) ^ ((rq & 7) << 4);
            *(short8v*)((char*)s_qka + off) = o.s;
        }
    }
    // stage t1 = relu(dpos@pm_w1 + pm_b1): 16 threads cover 2 rows each
    #pragma unroll
    for (int rr2 = 0; rr2 < 2; ++rr2) {
        int row = rt * 2 + rr2;
        float4 dp = *(const float4*)(&s_dp[row][0]);
        PK8 o;
        #pragma unroll
        for (int p = 0; p < 4; ++p) {
            float v0 = fmaxf(fmaf(dp.x, w1xr[2 * p],
                       fmaf(dp.y, w1yr[2 * p], fmaf(dp.z, w1zr[2 * p], w1br[2 * p]))), 0.f);
            float v1 = fmaxf(fmaf(dp.x, w1xr[2 * p + 1],
                       fmaf(dp.y, w1yr[2 * p + 1], fmaf(dp.z, w1zr[2 * p + 1], w1br[2 * p + 1]))), 0.f);
            o.u[p] = f2bf_pk(v0, v1);
        }
        int off = (row * 256 + ct8 * 2) ^ ((row & 7) << 4);
        *(short8v*)((char*)s_t1 + off) = o.s;
    }
    __syncthreads();   // A: tiles staged

    // GEMM: acc[mt][nt] = pre[col=jw+nt*16+lg*4+r][edge=mt*16+ln15]
    f32x4 acc[2][2];
    const f32x4 zz = {0.f, 0.f, 0.f, 0.f};
    #pragma unroll
    for (int mt = 0; mt < 2; ++mt) { acc[mt][0] = zz; acc[mt][1] = zz; }
    #pragma unroll
    for (int mt = 0; mt < 2; ++mt) {
        int row = mt * 16 + ln15;
        #pragma unroll
        for (int ks = 0; ks < 4; ++ks) {
            int off = (row * 256 + (ks * 32 + lg * 8) * 2) ^ ((row & 7) << 4);
            frag16 b = *(const frag16*)((const char*)s_t1 + off);
            acc[mt][0] = MFMA16(aW[0][ks], b, acc[mt][0]);
            acc[mt][1] = MFMA16(aW[1][ks], b, acc[mt][1]);
        }
    }

    // epilogue: + qka + bias_c, relu, dot at_w2, reduce
    #pragma unroll
    for (int mt = 0; mt < 2; ++mt) {
        int edge = mt * 16 + ln15;
        float p = 0.f;
        #pragma unroll
        for (int nt = 0; nt < 2; ++nt) {
            int col0 = jw + nt * 16 + lg * 4;
            int off = (edge * 256 + col0 * 2) ^ ((edge & 7) << 4);
            ushort4 qk = *(const ushort4*)((const char*)s_qka + off);
            float t0 = fmaxf(acc[mt][nt][0] + bf2f(qk.x) + bcv[nt * 4 + 0], 0.f);
            float t1v = fmaxf(acc[mt][nt][1] + bf2f(qk.y) + bcv[nt * 4 + 1], 0.f);
            float t2v = fmaxf(acc[mt][nt][2] + bf2f(qk.z) + bcv[nt * 4 + 2], 0.f);
            float t3v = fmaxf(acc[mt][nt][3] + bf2f(qk.w) + bcv[nt * 4 + 3], 0.f);
            p = fmaf(t0, w2v[nt * 4 + 0], p);
            p = fmaf(t1v, w2v[nt * 4 + 1], p);
            p = fmaf(t2v, w2v[nt * 4 + 2], p);
            p = fmaf(t3v, w2v[nt * 4 + 3], p);
        }
        p += __shfl_xor(p, 16, 64);
        p += __shfl_xor(p, 32, 64);
        if (lane < 16) s_logit[edge][wv] = p;
    }
    __syncthreads();   // B: s_logit ready

    if (t < TEDGE)
        logits[s0 + t] = s_logit[t][0] + s_logit[t][1]
                       + s_logit[t][2] + s_logit[t][3] + atb2;
}

// ---------------- K4: fused softmax + gather, one wave per node -------------
// 16-wide unrolled inner loop -> a whole avg-degree node's row-gathers in flight.
__global__ __launch_bounds__(256) void gather_kernel(
    const int* __restrict__ offsets, const int* __restrict__ rows_sorted,
    const float* __restrict__ dpos4, const float* __restrict__ logits,
    const unsigned short* __restrict__ vbf,
    const float* __restrict__ pm_w1, const float* __restrict__ pm_b1,
    float* __restrict__ out, unsigned short* __restrict__ ubf)
{
    const int n = blockIdx.x * 4 + (threadIdx.x >> 6);
    if (n >= NN) return;
    const int lane = threadIdx.x & 63;
    const int j0 = lane * 2;
    const int o0 = offsets[n], o1 = offsets[n + 1];
    const int deg = o1 - o0;

    const float w1x0 = pm_w1[j0],     w1y0 = pm_w1[C + j0];
    const float w1z0 = pm_w1[2 * C + j0], b10 = pm_b1[j0];
    const float w1x1 = pm_w1[j0 + 1], w1y1 = pm_w1[C + j0 + 1];
    const float w1z1 = pm_w1[2 * C + j0 + 1], b11 = pm_b1[j0 + 1];

    float accv0 = 0.f, accv1 = 0.f, acct0 = 0.f, acct1 = 0.f;

#define GBODY(I)                                                               \
    {                                                                          \
        float wt = __shfl(wreg, (I), 64);                                      \
        int   rv = __shfl(rreg, (I), 64);                                      \
        float dx = __shfl(dpx, (I), 64);                                       \
        float dy = __shfl(dpy, (I), 64);                                       \
        float dz = __shfl(dpz, (I), 64);                                       \
        unsigned int v2 = *(const unsigned int*)(vbf + (size_t)rv * C + j0);   \
        float va = bf2f((unsigned short)(v2 & 0xffffu));                       \
        float vb = bf2f((unsigned short)(v2 >> 16));                           \
        float t10 = fmaxf(fmaf(dx, w1x0, fmaf(dy, w1y0, fmaf(dz, w1z0, b10))), 0.f); \
        float t11 = fmaxf(fmaf(dx, w1x1, fmaf(dy, w1y1, fmaf(dz, w1z1, b11))), 0.f); \
        accv0 = fmaf(wt, va, accv0); accv1 = fmaf(wt, vb, accv1);              \
        acct0 = fmaf(wt, t10, acct0); acct1 = fmaf(wt, t11, acct1);            \
    }

    if (deg <= 64) {
        float lg = -1e30f; int rreg = 0;
        float dpx = 0.f, dpy = 0.f, dpz = 0.f;
        float wreg = 0.f;
        if (lane < deg) {
            lg = logits[o0 + lane];
            rreg = rows_sorted[o0 + lane];
            float4 dp = *(const float4*)(dpos4 + (size_t)(o0 + lane) * 4);
            dpx = dp.x; dpy = dp.y; dpz = dp.z;
        }
        float m = lg;
        #pragma unroll
        for (int d = 1; d < 64; d <<= 1) m = fmaxf(m, __shfl_xor(m, d, 64));
        float ew = (lane < deg) ? __expf(lg - m) : 0.f;
        float s = ew;
        #pragma unroll
        for (int d = 1; d < 64; d <<= 1) s += __shfl_xor(s, d, 64);
        wreg = ew * ((s > 0.f) ? 1.f / s : 0.f);

        int cnt16 = (deg + 15) & ~15;
        for (int i = 0; i < cnt16; i += 16) {
            GBODY(i);      GBODY(i + 1);  GBODY(i + 2);  GBODY(i + 3);
            GBODY(i + 4);  GBODY(i + 5);  GBODY(i + 6);  GBODY(i + 7);
            GBODY(i + 8);  GBODY(i + 9);  GBODY(i + 10); GBODY(i + 11);
            GBODY(i + 12); GBODY(i + 13); GBODY(i + 14); GBODY(i + 15);
        }
    } else {
        // generic chunked path (rare)
        float m = -1e30f;
        for (int base = o0; base < o1; base += 64) {
            float lg = (base + lane < o1) ? logits[base + lane] : -1e30f;
            #pragma unroll
            for (int d = 1; d < 64; d <<= 1) lg = fmaxf(lg, __shfl_xor(lg, d, 64));
            m = fmaxf(m, lg);
        }
        float s = 0.f;
        for (int base = o0; base < o1; base += 64) {
            float ew = (base + lane < o1) ? __expf(logits[base + lane] - m) : 0.f;
            #pragma unroll
            for (int d = 1; d < 64; d <<= 1) ew += __shfl_xor(ew, d, 64);
            s += ew;
        }
        float inv = (s > 0.f) ? 1.f / s : 0.f;
        for (int base = o0; base < o1; base += 64) {
            int cnt = min(64, o1 - base);
            float wreg = 0.f; int rreg = 0;
            float dpx = 0.f, dpy = 0.f, dpz = 0.f;
            if (lane < cnt) {
                wreg = __expf(logits[base + lane] - m) * inv;
                rreg = rows_sorted[base + lane];
                float4 dp = *(const float4*)(dpos4 + (size_t)(base + lane) * 4);
                dpx = dp.x; dpy = dp.y; dpz = dp.z;
            }
            int cnt8 = (cnt + 7) & ~7;
            for (int i = 0; i < cnt8; i += 8) {
                GBODY(i);     GBODY(i + 1); GBODY(i + 2); GBODY(i + 3);
                GBODY(i + 4); GBODY(i + 5); GBODY(i + 6); GBODY(i + 7);
            }
        }
    }
#undef GBODY

    const size_t op = (size_t)n * C + j0;
    float2 o = *(float2*)(out + op);
    o.x += accv0; o.y += accv1;
    *(float2*)(out + op) = o;
    *(unsigned int*)(ubf + op) = f2bf_pk(acct0, acct1);
}

// ---------------- K5: out += u @ pm_w2 + pm_b2 ----------------
__global__ __launch_bounds__(256, 4) void final_gemm(
    const unsigned short* __restrict__ ubf, const unsigned short* __restrict__ Wp2T,
    const float* __restrict__ pm_b2, float* __restrict__ out)
{
    __shared__ short s_u[64 * C];
    const int nb = blockIdx.x * 64;
    const int t = threadIdx.x;
    const int lane = t & 63, wv = t >> 6;
    const int ln15 = lane & 15, lg = lane >> 4;
    const int jw = wv * 32;

    {
        const int rq = t >> 2, q4 = t & 3;
        int row = nb + rq;
        #pragma unroll
        for (int i2 = 0; i2 < 4; ++i2) {
            int j0 = q4 * 32 + i2 * 8;
            short8v v = {0,0,0,0,0,0,0,0};
            if (row < NN) v = *(const short8v*)(ubf + (size_t)row * C + j0);
            int off = (rq * 256 + j0 * 2) ^ ((rq & 7) << 4);
            *(short8v*)((char*)s_u + off) = v;
        }
    }
    __syncthreads();

    frag16 aW[2][4];
    #pragma unroll
    for (int nt = 0; nt < 2; ++nt)
        #pragma unroll
        for (int ks = 0; ks < 4; ++ks)
            aW[nt][ks] = *(const frag16*)(Wp2T + (size_t)(jw + nt * 16 + ln15) * C
                                             + ks * 32 + lg * 8);
    f32x4 acc[4][2];
    const f32x4 zz = {0.f, 0.f, 0.f, 0.f};
    #pragma unroll
    for (int mt = 0; mt < 4; ++mt) { acc[mt][0] = zz; acc[mt][1] = zz; }

    #pragma unroll
    for (int mt = 0; mt < 4; ++mt) {
        int row = mt * 16 + ln15;
        #pragma unroll
        for (int ks = 0; ks < 4; ++ks) {
            int off = (row * 256 + (ks * 32 + lg * 8) * 2) ^ ((row & 7) << 4);
            frag16 b = *(const frag16*)((const char*)s_u + off);
            acc[mt][0] = MFMA16(aW[0][ks], b, acc[mt][0]);
            acc[mt][1] = MFMA16(aW[1][ks], b, acc[mt][1]);
        }
    }

    #pragma unroll
    for (int nt = 0; nt < 2; ++nt) {
        int col0 = jw + nt * 16 + lg * 4;
        float4 b2 = *(const float4*)(pm_b2 + col0);
        #pragma unroll
        for (int mt = 0; mt < 4; ++mt) {
            int node = nb + mt * 16 + ln15;
            if (node < NN) {
                float4 o = *(float4*)(out + (size_t)node * C + col0);
                o.x += acc[mt][nt][0] + b2.x; o.y += acc[mt][nt][1] + b2.y;
                o.z += acc[mt][nt][2] + b2.z; o.w += acc[mt][nt][3] + b2.w;
                *(float4*)(out + (size_t)node * C + col0) = o;
            }
        }
    }
}

// ---------------- launch ----------------
extern "C" void kernel_launch(void* const* d_in, const int* in_sizes, int n_in,
                              void* d_out, int out_size, void* d_ws, size_t ws_size,
                              hipStream_t stream)
{
    (void)in_sizes; (void)n_in; (void)out_size; (void)ws_size;
    const float* x      = (const float*)d_in[0];
    const float* pos    = (const float*)d_in[1];
    const int*   eidx   = (const int*)d_in[2];
    const float* Wq     = (const float*)d_in[3];
    const float* Wk     = (const float*)d_in[4];
    const float* Wv     = (const float*)d_in[5];
    const float* pm_w1  = (const float*)d_in[6];
    const float* pm_b1  = (const float*)d_in[7];
    const float* pm_w2  = (const float*)d_in[8];
    const float* pm_b2  = (const float*)d_in[9];
    const float* at_w1  = (const float*)d_in[10];
    const float* at_b1  = (const float*)d_in[11];
    const float* at_w2  = (const float*)d_in[12];
    const float* at_b2  = (const float*)d_in[13];
    const float* root_w = (const float*)d_in[14];
    const float* root_b = (const float*)d_in[15];
    float* out = (float*)d_out;

    char* w = (char*)d_ws;
    unsigned short* vbf  = (unsigned short*)w; w += (size_t)NN * C * 2;
    unsigned short* qabf = (unsigned short*)w; w += (size_t)NN * C * 2;
    unsigned short* kabf = (unsigned short*)w; w += (size_t)NN * C * 2;
    unsigned short* ubf  = (unsigned short*)w; w += (size_t)NN * C * 2;
    float* logits        = (float*)w; w += (size_t)EE * 4;
    float* dpos4         = (float*)w; w += (size_t)EE * 16;
    unsigned short* WcT  = (unsigned short*)w; w += (size_t)C * C * 2;
    unsigned short* WqaT = (unsigned short*)w; w += (size_t)C * C * 2;
    unsigned short* WkaT = (unsigned short*)w; w += (size_t)C * C * 2;
    unsigned short* WvT  = (unsigned short*)w; w += (size_t)C * C * 2;
    unsigned short* WrT  = (unsigned short*)w; w += (size_t)C * C * 2;
    unsigned short* Wp2T = (unsigned short*)w; w += (size_t)C * C * 2;
    float* bias_c        = (float*)w; w += 512;
    int* rows_sorted = (int*)w; w += (size_t)EE * 4;
    int* cols_sorted = (int*)w; w += (size_t)EE * 4;
    int* counts      = (int*)w; w += (size_t)NN * 4;
    int* cursor      = (int*)w; w += (size_t)NN * 4;   // adjacent to counts
    int* offsets     = (int*)w; w += (size_t)(NN + 1) * 4;

    hipMemsetAsync(counts, 0, (size_t)NN * 8, stream);   // counts + cursor

    prep_kernel<<<dim3(64, 7), 256, 0, stream>>>(
        pm_w2, at_w1, Wq, Wk, Wv, root_w, pm_b2, at_b1,
        WcT, WqaT, WkaT, WvT, WrT, Wp2T, bias_c);

    hist_kernel<<<(EE + 255) / 256, 256, 0, stream>>>(eidx, counts);
    scan_kernel<<<1, 1024, 0, stream>>>(counts, offsets, NN);
    fill_kernel<<<(EE + 255) / 256, 256, 0, stream>>>(
        eidx, pos, offsets, cursor, rows_sorted, cols_sorted, dpos4);

    node_gemm<<<(NN + 63) / 64, 256, 0, stream>>>(
        x, WvT, WqaT, WkaT, WrT, root_b, vbf, qabf, kabf, out);

    edge_kernel<<<NTILES, 256, 0, stream>>>(
        rows_sorted, cols_sorted, dpos4, qabf, kabf,
        pm_w1, pm_b1, WcT, bias_c, at_w2, at_b2, logits);

    gather_kernel<<<(NN + 3) / 4, 256, 0, stream>>>(
        offsets, rows_sorted, dpos4, logits, vbf, pm_w1, pm_b1, out, ubf);

    final_gemm<<<(NN + 63) / 64, 256, 0, stream>>>(ubf, Wp2T, pm_b2, out);
}

// Round 11
// 197.778 us; speedup vs baseline: 1.2717x; 1.2717x over previous
//
#include <hip/hip_runtime.h>
#include <hip/hip_bf16.h>

#define NN 30000
#define EE 480000
#define C  128
#define NTILES (EE / 64)   // 7500
#define SCAN_BLK 1024
#define NSCAN ((NN + SCAN_BLK - 1) / SCAN_BLK)   // 30

typedef __attribute__((ext_vector_type(8))) short          short8v;
typedef __attribute__((ext_vector_type(8))) unsigned short ushort8v;
typedef __attribute__((ext_vector_type(8))) short          frag16;   // 8 bf16
typedef __attribute__((ext_vector_type(4))) float          f32x4;

#define MFMA16(a, b, c) __builtin_amdgcn_mfma_f32_16x16x32_bf16(a, b, c, 0, 0, 0)

static __device__ __forceinline__ unsigned short f2bf_rn(float f) {
    unsigned int u = __float_as_uint(f);
    unsigned int r = (u + 0x7fffu + ((u >> 16) & 1u)) >> 16;
    return (unsigned short)r;
}
static __device__ __forceinline__ float bf2f(unsigned short s) {
    return __uint_as_float(((unsigned int)s) << 16);
}
// HW packed convert: 2 f32 -> 1 dword (2x bf16). gfx950-only (T12).
static __device__ __forceinline__ unsigned int f2bf_pk(float lo, float hi) {
    unsigned int r;
    asm("v_cvt_pk_bf16_f32 %0, %1, %2" : "=v"(r) : "v"(lo), "v"(hi));
    return r;
}
union PK8 { short8v s; unsigned int u[4]; };
union PK4 { ushort4 q; unsigned int u[2]; };

// ---------------- P0: weight precomputes (all outputs TRANSPOSED bf16) ------
__global__ __launch_bounds__(256) void prep_kernel(
    const float* __restrict__ pm_w2, const float* __restrict__ at_w1,
    const float* __restrict__ Wq, const float* __restrict__ Wk,
    const float* __restrict__ Wv, const float* __restrict__ root_w,
    const float* __restrict__ pm_b2, const float* __restrict__ at_b1,
    unsigned short* __restrict__ WcT, unsigned short* __restrict__ WqaT,
    unsigned short* __restrict__ WkaT, unsigned short* __restrict__ WvT,
    unsigned short* __restrict__ WrT, unsigned short* __restrict__ Wp2T,
    float* __restrict__ bias_c)
{
    const int which = blockIdx.y;
    const int t = threadIdx.x;
    const int i = blockIdx.x * 2 + (t >> 7), j = t & 127;

    if (which == 3) {
        if (blockIdx.x == 0 && t < C) {
            float s = at_b1[t];
            for (int k = 0; k < C; ++k) s = fmaf(pm_b2[k], at_w1[k * C + t], s);
            bias_c[t] = s;
        }
        return;
    }
    if (which >= 4) {
        const float* A = (which == 4) ? Wv : (which == 5) ? root_w : pm_w2;
        unsigned short* OT = (which == 4) ? WvT : (which == 5) ? WrT : Wp2T;
        OT[j * C + i] = f2bf_rn(A[i * C + j]);
        return;
    }
    const float* A = (which == 0) ? pm_w2 : (which == 1) ? Wq : Wk;
    unsigned short* OT = (which == 0) ? WcT : (which == 1) ? WqaT : WkaT;

    __shared__ float sA[2][C];
    sA[t >> 7][j] = A[i * C + j];
    __syncthreads();
    float s = 0.f;
    for (int k = 0; k < C; ++k) s = fmaf(sA[t >> 7][k], at_w1[k * C + j], s);
    OT[j * C + i] = f2bf_rn(s);
}

// ---------------- K1: node GEMMs via MFMA (stages f32 x -> bf16 LDS) --------
__global__ __launch_bounds__(256, 4) void node_gemm(
    const float* __restrict__ x,
    const unsigned short* __restrict__ WvT, const unsigned short* __restrict__ WqaT,
    const unsigned short* __restrict__ WkaT, const unsigned short* __restrict__ WrT,
    const float* __restrict__ root_b,
    unsigned short* __restrict__ vbf, unsigned short* __restrict__ qabf,
    unsigned short* __restrict__ kabf, float* __restrict__ out)
{
    __shared__ short s_x[64 * C];   // bf16, swizzled
    const int nb = blockIdx.x * 64;
    const int t = threadIdx.x;
    const int lane = t & 63, wv = t >> 6;
    const int ln15 = lane & 15, lg = lane >> 4;
    const int jw = wv * 32;

    {   // stage x tile (f32 -> bf16, packed converts)
        const int rq = t >> 2, q4 = t & 3;
        int row = nb + rq;
        #pragma unroll
        for (int i2 = 0; i2 < 4; ++i2) {
            int j0 = q4 * 32 + i2 * 8;
            PK8 o;
            if (row < NN) {
                float4 a = *(const float4*)(x + (size_t)row * C + j0);
                float4 b = *(const float4*)(x + (size_t)row * C + j0 + 4);
                o.u[0] = f2bf_pk(a.x, a.y);
                o.u[1] = f2bf_pk(a.z, a.w);
                o.u[2] = f2bf_pk(b.x, b.y);
                o.u[3] = f2bf_pk(b.z, b.w);
            } else {
                o.u[0] = o.u[1] = o.u[2] = o.u[3] = 0u;
            }
            int off = (rq * 256 + j0 * 2) ^ ((rq & 7) << 4);
            *(short8v*)((char*)s_x + off) = o.s;
        }
    }
    __syncthreads();

    for (int m = 0; m < 4; ++m) {
        const unsigned short* WT;
        switch (m) {
            case 0: WT = WvT;  break; case 1: WT = WqaT; break;
            case 2: WT = WkaT; break; default: WT = WrT;
        }
        frag16 aW[2][4];
        #pragma unroll
        for (int nt = 0; nt < 2; ++nt)
            #pragma unroll
            for (int ks = 0; ks < 4; ++ks)
                aW[nt][ks] = *(const frag16*)(WT + (size_t)(jw + nt * 16 + ln15) * C
                                                 + ks * 32 + lg * 8);
        f32x4 acc[4][2];
        const f32x4 zz = {0.f, 0.f, 0.f, 0.f};
        #pragma unroll
        for (int mt = 0; mt < 4; ++mt) { acc[mt][0] = zz; acc[mt][1] = zz; }

        #pragma unroll
        for (int mt = 0; mt < 4; ++mt) {
            int row = mt * 16 + ln15;
            #pragma unroll
            for (int ks = 0; ks < 4; ++ks) {
                int off = (row * 256 + (ks * 32 + lg * 8) * 2) ^ ((row & 7) << 4);
                frag16 b = *(const frag16*)((const char*)s_x + off);
                acc[mt][0] = MFMA16(aW[0][ks], b, acc[mt][0]);
                acc[mt][1] = MFMA16(aW[1][ks], b, acc[mt][1]);
            }
        }

        if (m == 3) {
            #pragma unroll
            for (int nt = 0; nt < 2; ++nt) {
                int col0 = jw + nt * 16 + lg * 4;
                float4 rb = *(const float4*)(root_b + col0);
                #pragma unroll
                for (int mt = 0; mt < 4; ++mt) {
                    int node = nb + mt * 16 + ln15;
                    if (node < NN) {
                        float4 o;
                        o.x = acc[mt][nt][0] + rb.x; o.y = acc[mt][nt][1] + rb.y;
                        o.z = acc[mt][nt][2] + rb.z; o.w = acc[mt][nt][3] + rb.w;
                        *(float4*)(out + (size_t)node * C + col0) = o;
                    }
                }
            }
        } else {
            unsigned short* OB = (m == 0) ? vbf : (m == 1) ? qabf : kabf;
            #pragma unroll
            for (int nt = 0; nt < 2; ++nt) {
                int col0 = jw + nt * 16 + lg * 4;
                #pragma unroll
                for (int mt = 0; mt < 4; ++mt) {
                    int node = nb + mt * 16 + ln15;
                    if (node < NN) {
                        PK4 cv;
                        cv.u[0] = f2bf_pk(acc[mt][nt][0], acc[mt][nt][1]);
                        cv.u[1] = f2bf_pk(acc[mt][nt][2], acc[mt][nt][3]);
                        *(ushort4*)(OB + (size_t)node * C + col0) = cv.q;
                    }
                }
            }
        }
    }
}

// ---------------- K3: CSR build by destination ----------------
__global__ __launch_bounds__(256) void hist_kernel(const int* __restrict__ eidx,
                                                   int* __restrict__ counts)
{
    int e = blockIdx.x * 256 + threadIdx.x;
    if (e < EE) atomicAdd(&counts[eidx[EE + e]], 1);
}

// multi-block exclusive scan: scan1 (local) -> scan2 (block sums) -> scan3 (add)
__global__ __launch_bounds__(1024) void scan1_kernel(const int* __restrict__ counts,
                                                     int* __restrict__ offsets,
                                                     int* __restrict__ bsums)
{
    __shared__ int wsum[16];
    __shared__ int wpre[16];
    const int t = threadIdx.x;
    const int lane = t & 63, w = t >> 6;
    const int i = blockIdx.x * SCAN_BLK + t;
    int v = (i < NN) ? counts[i] : 0;
    int incl = v;
    #pragma unroll
    for (int d = 1; d < 64; d <<= 1) {
        int u = __shfl_up(incl, d, 64);
        if (lane >= d) incl += u;
    }
    if (lane == 63) wsum[w] = incl;
    __syncthreads();
    if (t == 0) {
        int run = 0;
        #pragma unroll
        for (int ww = 0; ww < 16; ++ww) { wpre[ww] = run; run += wsum[ww]; }
    }
    __syncthreads();
    int excl = wpre[w] + incl - v;
    if (i < NN) offsets[i] = excl;
    if (t == SCAN_BLK - 1) bsums[blockIdx.x] = excl + v;
}

__global__ __launch_bounds__(64) void scan2_kernel(int* __restrict__ bsums,
                                                   int* __restrict__ offsets)
{
    const int lane = threadIdx.x;
    int v = (lane < NSCAN) ? bsums[lane] : 0;
    int incl = v;
    #pragma unroll
    for (int d = 1; d < 64; d <<= 1) {
        int u = __shfl_up(incl, d, 64);
        if (lane >= d) incl += u;
    }
    if (lane < NSCAN) bsums[lane] = incl - v;   // exclusive
    if (lane == 0) offsets[NN] = EE;            // total is known
}

__global__ __launch_bounds__(1024) void scan3_kernel(int* __restrict__ offsets,
                                                     const int* __restrict__ bsums)
{
    const int i = blockIdx.x * SCAN_BLK + threadIdx.x;
    if (i < NN) offsets[i] += bsums[blockIdx.x];
}

__global__ __launch_bounds__(256) void fill_kernel(const int* __restrict__ eidx,
                                                   const float* __restrict__ pos,
                                                   const int* __restrict__ offsets,
                                                   int* __restrict__ cursor,
                                                   int* __restrict__ rows_sorted,
                                                   int* __restrict__ cols_sorted,
                                                   float* __restrict__ dpos4)
{
    int e = blockIdx.x * 256 + threadIdx.x;
    if (e < EE) {
        int r = eidx[e];
        int c = eidx[EE + e];
        int p = atomicAdd(&cursor[c], 1);
        int slot = offsets[c] + p;
        rows_sorted[slot] = r;
        cols_sorted[slot] = c;
        float4 d;
        d.x = pos[r * 3 + 0] - pos[c * 3 + 0];
        d.y = pos[r * 3 + 1] - pos[c * 3 + 1];
        d.z = pos[r * 3 + 2] - pos[c * 3 + 2];
        d.w = 0.f;
        *(float4*)(dpos4 + (size_t)slot * 4) = d;
    }
}

// ---------------- K2: per-edge logits via MFMA (r8 structure, 1 tile/block) --
__global__ __launch_bounds__(256, 4) void edge_kernel(
    const int* __restrict__ rows_sorted, const int* __restrict__ cols_sorted,
    const float* __restrict__ dpos4,
    const unsigned short* __restrict__ qabf, const unsigned short* __restrict__ kabf,
    const float* __restrict__ pm_w1, const float* __restrict__ pm_b1,
    const unsigned short* __restrict__ WcT, const float* __restrict__ bias_c,
    const float* __restrict__ at_w2, const float* __restrict__ at_b2,
    float* __restrict__ logits)
{
    __shared__ short s_t1[64 * C];    // bf16, swizzled (16 KB)
    __shared__ short s_qka[64 * C];   // bf16, swizzled (16 KB)
    __shared__ float s_dp[64][4];
    __shared__ int   s_row[64], s_col[64];
    __shared__ float s_logit[64][4];

    const int t = threadIdx.x;
    const int lane = t & 63, wv = t >> 6;
    const int ln15 = lane & 15, lg = lane >> 4;
    const int jw = wv * 32;
    const int rt = t >> 4, ct8 = (t & 15) * 8;
    const int rq = t >> 2, q4 = t & 3;
    const int s0 = blockIdx.x * 64;

    // metadata stage (read once by 64 threads)
    if (t < 64) {
        s_row[t] = rows_sorted[s0 + t];
        s_col[t] = cols_sorted[s0 + t];
        *(float4*)(&s_dp[t][0]) = *(const float4*)(dpos4 + (size_t)(s0 + t) * 4);
    }

    // pm_w1/pm_b1 slice in registers
    float w1xr[8], w1yr[8], w1zr[8], w1br[8];
    #pragma unroll
    for (int e = 0; e < 8; ++e) {
        int j = ct8 + e;
        w1xr[e] = pm_w1[j];
        w1yr[e] = pm_w1[C + j];
        w1zr[e] = pm_w1[2 * C + j];
        w1br[e] = pm_b1[j];
    }

    // per-lane epilogue constants: cols jw + nt*16 + lg*4 + r
    float bcv[8], w2v[8];
    #pragma unroll
    for (int nt = 0; nt < 2; ++nt) {
        int col0 = jw + nt * 16 + lg * 4;
        float4 b4 = *(const float4*)(bias_c + col0);
        float4 w4 = *(const float4*)(at_w2 + col0);
        bcv[nt * 4 + 0] = b4.x; bcv[nt * 4 + 1] = b4.y;
        bcv[nt * 4 + 2] = b4.z; bcv[nt * 4 + 3] = b4.w;
        w2v[nt * 4 + 0] = w4.x; w2v[nt * 4 + 1] = w4.y;
        w2v[nt * 4 + 2] = w4.z; w2v[nt * 4 + 3] = w4.w;
    }
    const float atb2 = at_b2[0];

    frag16 aW[2][4];
    #pragma unroll
    for (int nt = 0; nt < 2; ++nt)
        #pragma unroll
        for (int ks = 0; ks < 4; ++ks)
            aW[nt][ks] = *(const frag16*)(WcT + (size_t)(jw + nt * 16 + ln15) * C
                                             + ks * 32 + lg * 8);
    __syncthreads();   // metadata ready

    // stage qka = qa[col] - ka[row]  (row-granular loads, packed converts)
    {
        const unsigned short* qrow = qabf + (size_t)s_col[rq] * C;
        const unsigned short* krow = kabf + (size_t)s_row[rq] * C;
        #pragma unroll
        for (int i2 = 0; i2 < 4; ++i2) {
            int j0 = q4 * 32 + i2 * 8;
            ushort8v qa8 = *(const ushort8v*)(qrow + j0);
            ushort8v ka8 = *(const ushort8v*)(krow + j0);
            PK8 o;
            #pragma unroll
            for (int p = 0; p < 4; ++p) {
                float a0 = bf2f(qa8[2 * p])     - bf2f(ka8[2 * p]);
                float a1 = bf2f(qa8[2 * p + 1]) - bf2f(ka8[2 * p + 1]);
                o.u[p] = f2bf_pk(a0, a1);
            }
            int off = (rq * 256 + j0 * 2) ^ ((rq & 7) << 4);
            *(short8v*)((char*)s_qka + off) = o.s;
        }
    }
    // stage t1 = relu(dpos@pm_w1 + pm_b1) (packed converts)
    #pragma unroll
    for (int rr2 = 0; rr2 < 4; ++rr2) {
        int row = rt * 4 + rr2;
        float4 dp = *(const float4*)(&s_dp[row][0]);
        PK8 o;
        #pragma unroll
        for (int p = 0; p < 4; ++p) {
            float v0 = fmaxf(fmaf(dp.x, w1xr[2 * p],
                       fmaf(dp.y, w1yr[2 * p], fmaf(dp.z, w1zr[2 * p], w1br[2 * p]))), 0.f);
            float v1 = fmaxf(fmaf(dp.x, w1xr[2 * p + 1],
                       fmaf(dp.y, w1yr[2 * p + 1], fmaf(dp.z, w1zr[2 * p + 1], w1br[2 * p + 1]))), 0.f);
            o.u[p] = f2bf_pk(v0, v1);
        }
        int off = (row * 256 + ct8 * 2) ^ ((row & 7) << 4);
        *(short8v*)((char*)s_t1 + off) = o.s;
    }
    __syncthreads();   // A: tiles staged

    // GEMM: acc[mt][nt] = pre[col=jw+nt*16+lg*4+r][edge=mt*16+ln15]
    f32x4 acc[4][2];
    const f32x4 zz = {0.f, 0.f, 0.f, 0.f};
    #pragma unroll
    for (int mt = 0; mt < 4; ++mt) { acc[mt][0] = zz; acc[mt][1] = zz; }
    #pragma unroll
    for (int mt = 0; mt < 4; ++mt) {
        int row = mt * 16 + ln15;
        #pragma unroll
        for (int ks = 0; ks < 4; ++ks) {
            int off = (row * 256 + (ks * 32 + lg * 8) * 2) ^ ((row & 7) << 4);
            frag16 b = *(const frag16*)((const char*)s_t1 + off);
            acc[mt][0] = MFMA16(aW[0][ks], b, acc[mt][0]);
            acc[mt][1] = MFMA16(aW[1][ks], b, acc[mt][1]);
        }
    }

    // epilogue: + qka + bias_c, relu, dot at_w2, reduce
    #pragma unroll
    for (int mt = 0; mt < 4; ++mt) {
        int edge = mt * 16 + ln15;
        float p = 0.f;
        #pragma unroll
        for (int nt = 0; nt < 2; ++nt) {
            int col0 = jw + nt * 16 + lg * 4;
            int off = (edge * 256 + col0 * 2) ^ ((edge & 7) << 4);
            ushort4 qk = *(const ushort4*)((const char*)s_qka + off);
            float t0 = fmaxf(acc[mt][nt][0] + bf2f(qk.x) + bcv[nt * 4 + 0], 0.f);
            float t1v = fmaxf(acc[mt][nt][1] + bf2f(qk.y) + bcv[nt * 4 + 1], 0.f);
            float t2v = fmaxf(acc[mt][nt][2] + bf2f(qk.z) + bcv[nt * 4 + 2], 0.f);
            float t3v = fmaxf(acc[mt][nt][3] + bf2f(qk.w) + bcv[nt * 4 + 3], 0.f);
            p = fmaf(t0, w2v[nt * 4 + 0], p);
            p = fmaf(t1v, w2v[nt * 4 + 1], p);
            p = fmaf(t2v, w2v[nt * 4 + 2], p);
            p = fmaf(t3v, w2v[nt * 4 + 3], p);
        }
        p += __shfl_xor(p, 16, 64);
        p += __shfl_xor(p, 32, 64);
        if (lane < 16) s_logit[edge][wv] = p;
    }
    __syncthreads();   // B: s_logit ready

    if (t < 64)
        logits[s0 + t] = s_logit[t][0] + s_logit[t][1]
                       + s_logit[t][2] + s_logit[t][3] + atb2;
}

// ---------------- K4: fused softmax + gather, one wave per node -------------
__global__ __launch_bounds__(256) void gather_kernel(
    const int* __restrict__ offsets, const int* __restrict__ rows_sorted,
    const float* __restrict__ dpos4, const float* __restrict__ logits,
    const unsigned short* __restrict__ vbf,
    const float* __restrict__ pm_w1, const float* __restrict__ pm_b1,
    float* __restrict__ out, unsigned short* __restrict__ ubf)
{
    const int n = blockIdx.x * 4 + (threadIdx.x >> 6);
    if (n >= NN) return;
    const int lane = threadIdx.x & 63;
    const int j0 = lane * 2;
    const int o0 = offsets[n], o1 = offsets[n + 1];
    const int deg = o1 - o0;

    const float w1x0 = pm_w1[j0],     w1y0 = pm_w1[C + j0];
    const float w1z0 = pm_w1[2 * C + j0], b10 = pm_b1[j0];
    const float w1x1 = pm_w1[j0 + 1], w1y1 = pm_w1[C + j0 + 1];
    const float w1z1 = pm_w1[2 * C + j0 + 1], b11 = pm_b1[j0 + 1];

    float accv0 = 0.f, accv1 = 0.f, acct0 = 0.f, acct1 = 0.f;

#define GBODY(I)                                                               \
    {                                                                          \
        float wt = __shfl(wreg, (I), 64);                                      \
        int   rv = __shfl(rreg, (I), 64);                                      \
        float dx = __shfl(dpx, (I), 64);                                       \
        float dy = __shfl(dpy, (I), 64);                                       \
        float dz = __shfl(dpz, (I), 64);                                       \
        unsigned int v2 = *(const unsigned int*)(vbf + (size_t)rv * C + j0);   \
        float va = bf2f((unsigned short)(v2 & 0xffffu));                       \
        float vb = bf2f((unsigned short)(v2 >> 16));                           \
        float t10 = fmaxf(fmaf(dx, w1x0, fmaf(dy, w1y0, fmaf(dz, w1z0, b10))), 0.f); \
        float t11 = fmaxf(fmaf(dx, w1x1, fmaf(dy, w1y1, fmaf(dz, w1z1, b11))), 0.f); \
        accv0 = fmaf(wt, va, accv0); accv1 = fmaf(wt, vb, accv1);              \
        acct0 = fmaf(wt, t10, acct0); acct1 = fmaf(wt, t11, acct1);            \
    }

    if (deg <= 64) {
        float lg = -1e30f; int rreg = 0;
        float dpx = 0.f, dpy = 0.f, dpz = 0.f;
        float wreg = 0.f;
        if (lane < deg) {
            lg = logits[o0 + lane];
            rreg = rows_sorted[o0 + lane];
            float4 dp = *(const float4*)(dpos4 + (size_t)(o0 + lane) * 4);
            dpx = dp.x; dpy = dp.y; dpz = dp.z;
        }
        float m = lg;
        #pragma unroll
        for (int d = 1; d < 64; d <<= 1) m = fmaxf(m, __shfl_xor(m, d, 64));
        float ew = (lane < deg) ? __expf(lg - m) : 0.f;
        float s = ew;
        #pragma unroll
        for (int d = 1; d < 64; d <<= 1) s += __shfl_xor(s, d, 64);
        wreg = ew * ((s > 0.f) ? 1.f / s : 0.f);

        int cnt8 = (deg + 7) & ~7;
        for (int i = 0; i < cnt8; i += 8) {
            GBODY(i);     GBODY(i + 1); GBODY(i + 2); GBODY(i + 3);
            GBODY(i + 4); GBODY(i + 5); GBODY(i + 6); GBODY(i + 7);
        }
    } else {
        // generic chunked path (rare)
        float m = -1e30f;
        for (int base = o0; base < o1; base += 64) {
            float lg = (base + lane < o1) ? logits[base + lane] : -1e30f;
            #pragma unroll
            for (int d = 1; d < 64; d <<= 1) lg = fmaxf(lg, __shfl_xor(lg, d, 64));
            m = fmaxf(m, lg);
        }
        float s = 0.f;
        for (int base = o0; base < o1; base += 64) {
            float ew = (base + lane < o1) ? __expf(logits[base + lane] - m) : 0.f;
            #pragma unroll
            for (int d = 1; d < 64; d <<= 1) ew += __shfl_xor(ew, d, 64);
            s += ew;
        }
        float inv = (s > 0.f) ? 1.f / s : 0.f;
        for (int base = o0; base < o1; base += 64) {
            int cnt = min(64, o1 - base);
            float wreg = 0.f; int rreg = 0;
            float dpx = 0.f, dpy = 0.f, dpz = 0.f;
            if (lane < cnt) {
                wreg = __expf(logits[base + lane] - m) * inv;
                rreg = rows_sorted[base + lane];
                float4 dp = *(const float4*)(dpos4 + (size_t)(base + lane) * 4);
                dpx = dp.x; dpy = dp.y; dpz = dp.z;
            }
            int cnt8 = (cnt + 7) & ~7;
            for (int i = 0; i < cnt8; i += 8) {
                GBODY(i);     GBODY(i + 1); GBODY(i + 2); GBODY(i + 3);
                GBODY(i + 4); GBODY(i + 5); GBODY(i + 6); GBODY(i + 7);
            }
        }
    }
#undef GBODY

    const size_t op = (size_t)n * C + j0;
    float2 o = *(float2*)(out + op);
    o.x += accv0; o.y += accv1;
    *(float2*)(out + op) = o;
    *(unsigned int*)(ubf + op) = f2bf_pk(acct0, acct1);
}

// ---------------- K5: out += u @ pm_w2 + pm_b2 ----------------
__global__ __launch_bounds__(256, 4) void final_gemm(
    const unsigned short* __restrict__ ubf, const unsigned short* __restrict__ Wp2T,
    const float* __restrict__ pm_b2, float* __restrict__ out)
{
    __shared__ short s_u[64 * C];
    const int nb = blockIdx.x * 64;
    const int t = threadIdx.x;
    const int lane = t & 63, wv = t >> 6;
    const int ln15 = lane & 15, lg = lane >> 4;
    const int jw = wv * 32;

    {
        const int rq = t >> 2, q4 = t & 3;
        int row = nb + rq;
        #pragma unroll
        for (int i2 = 0; i2 < 4; ++i2) {
            int j0 = q4 * 32 + i2 * 8;
            short8v v = {0,0,0,0,0,0,0,0};
            if (row < NN) v = *(const short8v*)(ubf + (size_t)row * C + j0);
            int off = (rq * 256 + j0 * 2) ^ ((rq & 7) << 4);
            *(short8v*)((char*)s_u + off) = v;
        }
    }
    __syncthreads();

    frag16 aW[2][4];
    #pragma unroll
    for (int nt = 0; nt < 2; ++nt)
        #pragma unroll
        for (int ks = 0; ks < 4; ++ks)
            aW[nt][ks] = *(const frag16*)(Wp2T + (size_t)(jw + nt * 16 + ln15) * C
                                             + ks * 32 + lg * 8);
    f32x4 acc[4][2];
    const f32x4 zz = {0.f, 0.f, 0.f, 0.f};
    #pragma unroll
    for (int mt = 0; mt < 4; ++mt) { acc[mt][0] = zz; acc[mt][1] = zz; }

    #pragma unroll
    for (int mt = 0; mt < 4; ++mt) {
        int row = mt * 16 + ln15;
        #pragma unroll
        for (int ks = 0; ks < 4; ++ks) {
            int off = (row * 256 + (ks * 32 + lg * 8) * 2) ^ ((row & 7) << 4);
            frag16 b = *(const frag16*)((const char*)s_u + off);
            acc[mt][0] = MFMA16(aW[0][ks], b, acc[mt][0]);
            acc[mt][1] = MFMA16(aW[1][ks], b, acc[mt][1]);
        }
    }

    #pragma unroll
    for (int nt = 0; nt < 2; ++nt) {
        int col0 = jw + nt * 16 + lg * 4;
        float4 b2 = *(const float4*)(pm_b2 + col0);
        #pragma unroll
        for (int mt = 0; mt < 4; ++mt) {
            int node = nb + mt * 16 + ln15;
            if (node < NN) {
                float4 o = *(float4*)(out + (size_t)node * C + col0);
                o.x += acc[mt][nt][0] + b2.x; o.y += acc[mt][nt][1] + b2.y;
                o.z += acc[mt][nt][2] + b2.z; o.w += acc[mt][nt][3] + b2.w;
                *(float4*)(out + (size_t)node * C + col0) = o;
            }
        }
    }
}

// ---------------- launch ----------------
extern "C" void kernel_launch(void* const* d_in, const int* in_sizes, int n_in,
                              void* d_out, int out_size, void* d_ws, size_t ws_size,
                              hipStream_t stream)
{
    (void)in_sizes; (void)n_in; (void)out_size; (void)ws_size;
    const float* x      = (const float*)d_in[0];
    const float* pos    = (const float*)d_in[1];
    const int*   eidx   = (const int*)d_in[2];
    const float* Wq     = (const float*)d_in[3];
    const float* Wk     = (const float*)d_in[4];
    const float* Wv     = (const float*)d_in[5];
    const float* pm_w1  = (const float*)d_in[6];
    const float* pm_b1  = (const float*)d_in[7];
    const float* pm_w2  = (const float*)d_in[8];
    const float* pm_b2  = (const float*)d_in[9];
    const float* at_w1  = (const float*)d_in[10];
    const float* at_b1  = (const float*)d_in[11];
    const float* at_w2  = (const float*)d_in[12];
    const float* at_b2  = (const float*)d_in[13];
    const float* root_w = (const float*)d_in[14];
    const float* root_b = (const float*)d_in[15];
    float* out = (float*)d_out;

    char* w = (char*)d_ws;
    unsigned short* vbf  = (unsigned short*)w; w += (size_t)NN * C * 2;
    unsigned short* qabf = (unsigned short*)w; w += (size_t)NN * C * 2;
    unsigned short* kabf = (unsigned short*)w; w += (size_t)NN * C * 2;
    unsigned short* ubf  = (unsigned short*)w; w += (size_t)NN * C * 2;
    float* logits        = (float*)w; w += (size_t)EE * 4;
    float* dpos4         = (float*)w; w += (size_t)EE * 16;
    unsigned short* WcT  = (unsigned short*)w; w += (size_t)C * C * 2;
    unsigned short* WqaT = (unsigned short*)w; w += (size_t)C * C * 2;
    unsigned short* WkaT = (unsigned short*)w; w += (size_t)C * C * 2;
    unsigned short* WvT  = (unsigned short*)w; w += (size_t)C * C * 2;
    unsigned short* WrT  = (unsigned short*)w; w += (size_t)C * C * 2;
    unsigned short* Wp2T = (unsigned short*)w; w += (size_t)C * C * 2;
    float* bias_c        = (float*)w; w += 512;
    int* rows_sorted = (int*)w; w += (size_t)EE * 4;
    int* cols_sorted = (int*)w; w += (size_t)EE * 4;
    int* counts      = (int*)w; w += (size_t)NN * 4;
    int* cursor      = (int*)w; w += (size_t)NN * 4;   // adjacent to counts
    int* offsets     = (int*)w; w += (size_t)(NN + 1) * 4;
    int* bsums       = (int*)w; w += 256;

    hipMemsetAsync(counts, 0, (size_t)NN * 8, stream);   // counts + cursor

    prep_kernel<<<dim3(64, 7), 256, 0, stream>>>(
        pm_w2, at_w1, Wq, Wk, Wv, root_w, pm_b2, at_b1,
        WcT, WqaT, WkaT, WvT, WrT, Wp2T, bias_c);

    hist_kernel<<<(EE + 255) / 256, 256, 0, stream>>>(eidx, counts);
    scan1_kernel<<<NSCAN, SCAN_BLK, 0, stream>>>(counts, offsets, bsums);
    scan2_kernel<<<1, 64, 0, stream>>>(bsums, offsets);
    scan3_kernel<<<NSCAN, SCAN_BLK, 0, stream>>>(offsets, bsums);
    fill_kernel<<<(EE + 255) / 256, 256, 0, stream>>>(
        eidx, pos, offsets, cursor, rows_sorted, cols_sorted, dpos4);

    node_gemm<<<(NN + 63) / 64, 256, 0, stream>>>(
        x, WvT, WqaT, WkaT, WrT, root_b, vbf, qabf, kabf, out);

    edge_kernel<<<NTILES, 256, 0, stream>>>(
        rows_sorted, cols_sorted, dpos4, qabf, kabf,
        pm_w1, pm_b1, WcT, bias_c, at_w2, at_b2, logits);

    gather_kernel<<<(NN + 3) / 4, 256, 0, stream>>>(
        offsets, rows_sorted, dpos4, logits, vbf, pm_w1, pm_b1, out, ubf);

    final_gemm<<<(NN + 63) / 64, 256, 0, stream>>>(ubf, Wp2T, pm_b2, out);
}